// Round 7
// baseline (1908.622 us; speedup 1.0000x reference)
//
#include <hip/hip_runtime.h>
#include <math.h>

typedef unsigned int uint;
typedef unsigned short ushort;
typedef __bf16 bf16x8 __attribute__((ext_vector_type(8)));
typedef float f32x4 __attribute__((ext_vector_type(4)));
typedef __attribute__((address_space(1))) const void gvoid;
typedef __attribute__((address_space(3))) void svoid;

__device__ __forceinline__ float b2f(ushort u) {
  uint v = ((uint)u) << 16;
  return __uint_as_float(v);
}
__device__ __forceinline__ ushort f2b(float f) {
  uint u = __float_as_uint(f);
  u += 0x7FFFu + ((u >> 16) & 1u);  // RNE
  return (ushort)(u >> 16);
}
__device__ __forceinline__ uint pack2(float a, float b) {
  return (uint)f2b(a) | ((uint)f2b(b) << 16);
}

// All feature buffers are SLICED: [slice][node][16 uints = 32 bf16 feats].
// F=256 -> 8 slices, F=128 -> 4 slices. slice = blockIdx % NS rides the
// round-robin block->XCD dispatch so each XCD's gathers stay in its 4MB L2.

// ---------------- preprocessing ----------------

__global__ void edge_kernel(const int* __restrict__ src, const int* __restrict__ dst,
                            const float* __restrict__ w, float* __restrict__ deg,
                            int* __restrict__ cnt, int ne) {
  int e = blockIdx.x * blockDim.x + threadIdx.x;
  if (e < ne) {
    atomicAdd(&deg[src[e]], w[e]);
    atomicAdd(&cnt[dst[e]], 1);
  }
}

__global__ __launch_bounds__(256) void node_kernel(float* __restrict__ deg,
                                                   const int* __restrict__ cnt,
                                                   int* __restrict__ rowstart,
                                                   int* __restrict__ cursor,
                                                   int* __restrict__ total,
                                                   const int* __restrict__ batch,
                                                   int nb, int ng, int* __restrict__ bnd) {
  __shared__ int ls[256];
  __shared__ int base;
  int tid = threadIdx.x;
  int i = blockIdx.x * 256 + tid;
  int c = (i < nb) ? cnt[i] : 0;
  ls[tid] = c;
  __syncthreads();
  for (int off = 1; off < 256; off <<= 1) {
    int v = (tid >= off) ? ls[tid - off] : 0;
    __syncthreads();
    ls[tid] += v;
    __syncthreads();
  }
  if (tid == 255) base = atomicAdd(total, ls[255]);
  __syncthreads();
  if (i < nb) {
    int pos = base + ls[tid] - c;
    rowstart[i] = pos;
    cursor[i] = pos;
    float d = deg[i];
    deg[i] = d > 0.f ? rsqrtf(fmaxf(d, 1e-30f)) : 0.f;
  }
  if (blockIdx.x == 0 && tid <= ng) {
    int lo = 0, hi = nb;
    while (lo < hi) {
      int mid = (lo + hi) >> 1;
      if (batch[mid] < tid) lo = mid + 1; else hi = mid;
    }
    bnd[tid] = lo;
  }
}

__global__ void scatter_kernel(const int* __restrict__ src, const int* __restrict__ dst,
                               const float* __restrict__ w, const float* __restrict__ dis,
                               int* __restrict__ cursor, int2* __restrict__ cv, int ne) {
  int e = blockIdx.x * blockDim.x + threadIdx.x;
  if (e < ne) {
    int d = dst[e], s = src[e];
    int pos = atomicAdd(&cursor[d], 1);
    float v = -(dis[s] * w[e] * dis[d]);
    cv[pos] = make_int2(s, __float_as_int(v));
  }
}

// ---------------- conversions ----------------

// x fp32 [NB][128] -> sliced bf16 pairs (NS=4)
__global__ void xcvt_kernel(const float* __restrict__ x, uint* __restrict__ o, int nb) {
  int id = blockIdx.x * blockDim.x + threadIdx.x;
  if (id >= nb * 64) return;
  int i = id >> 6, u = id & 63;
  float2 v = *(const float2*)(x + (size_t)i * 128 + u * 2);
  o[((size_t)(u >> 4) * nb + i) * 16 + (u & 15)] = pack2(v.x, v.y);
}

// W fp32 [5][Fin][256] -> WT bf16 [256][Ktot] dense, k = ord*Fin+fin
__global__ void wprep_kernel(const float* __restrict__ W, ushort* __restrict__ WT,
                             int shift, int Ktot, int total) {
  int id = blockIdx.x * blockDim.x + threadIdx.x;
  if (id >= total) return;
  int n = id / Ktot;
  int k = id - n * Ktot;
  int fin = k & ((1 << shift) - 1);
  int ord = k >> shift;
  WT[id] = f2b(W[(size_t)(ord << shift) * 256 + (size_t)fin * 256 + n]);
}

__global__ void wprep2_kernel(const float* __restrict__ W2, ushort* __restrict__ WT2,
                              const float* __restrict__ W3, ushort* __restrict__ WT3,
                              int tot) {
  int id = blockIdx.x * blockDim.x + threadIdx.x;
  if (id >= 2 * tot) return;
  const float* W = (id < tot) ? W2 : W3;
  ushort* WT = (id < tot) ? WT2 : WT3;
  int t = (id < tot) ? id : id - tot;
  int n = t / 1280;
  int k = t - n * 1280;
  int fin = k & 255;
  int ord = k >> 8;
  WT[t] = f2b(W[(size_t)(ord << 8) * 256 + (size_t)fin * 256 + n]);
}

// ---------------- SpMM, sliced: out[s][row] = alpha*sum val*X[s][col] - sub[s][row] ----
// block = 256 thr = 4 waves = 4 rows; wave = 4 groups x 16 lanes; group g edges stride-4.

template <int LOG2NS>
__global__ __launch_bounds__(256) void spmm_slice(const int* __restrict__ rowstart,
                                                  const int* __restrict__ rowcnt,
                                                  const int2* __restrict__ cv,
                                                  const uint* __restrict__ X,
                                                  uint* __restrict__ out,
                                                  const uint* __restrict__ sub,
                                                  float alpha, int nb) {
  constexpr int NS = 1 << LOG2NS;
  int s = blockIdx.x & (NS - 1);
  int row = (blockIdx.x >> LOG2NS) * 4 + (threadIdx.x >> 6);
  if (row >= nb) return;
  int l = threadIdx.x & 63;
  int g = l >> 4, u = l & 15;
  int e0 = __builtin_amdgcn_readfirstlane(rowstart[row]);
  int cnt = __builtin_amdgcn_readfirstlane(rowcnt[row]);
  int e1 = e0 + cnt;
  const uint* Xs = X + (size_t)s * nb * 16;
  float a0 = 0.f, a1 = 0.f;
  int e = e0 + g;
  for (; e + 4 < e1; e += 8) {  // 2 independent gathers in flight
    int2 p0 = cv[e];
    int2 p1 = cv[e + 4];
    uint x0 = Xs[(size_t)p0.x * 16 + u];
    uint x1 = Xs[(size_t)p1.x * 16 + u];
    float v0 = __int_as_float(p0.y), v1 = __int_as_float(p1.y);
    a0 = fmaf(v0, b2f((ushort)(x0 & 0xFFFF)), a0);
    a1 = fmaf(v0, b2f((ushort)(x0 >> 16)), a1);
    a0 = fmaf(v1, b2f((ushort)(x1 & 0xFFFF)), a0);
    a1 = fmaf(v1, b2f((ushort)(x1 >> 16)), a1);
  }
  if (e < e1) {
    int2 p0 = cv[e];
    uint x0 = Xs[(size_t)p0.x * 16 + u];
    float v0 = __int_as_float(p0.y);
    a0 = fmaf(v0, b2f((ushort)(x0 & 0xFFFF)), a0);
    a1 = fmaf(v0, b2f((ushort)(x0 >> 16)), a1);
  }
  a0 += __shfl_xor(a0, 16, 64);
  a0 += __shfl_xor(a0, 32, 64);
  a1 += __shfl_xor(a1, 16, 64);
  a1 += __shfl_xor(a1, 32, 64);
  if (g == 0) {
    float r0 = alpha * a0, r1 = alpha * a1;
    size_t oi = ((size_t)s * nb + row) * 16 + u;
    if (sub) {
      uint sv = sub[oi];
      r0 -= b2f((ushort)(sv & 0xFFFF));
      r1 -= b2f((ushort)(sv >> 16));
    }
    out[oi] = pack2(r0, r1);
  }
}

// ---------------- MFMA GEMM: C[M][256] = act(sum_ord Tx_ord @ W_ord + b) -> sliced bf16 ----
// A: 5 sliced bf16 buffers; WT dense [256][Ktot]; tile 128x128, BK=64.
// LDS linear dest for global_load_lds; XOR swizzle ((row&7)<<4) applied on the
// global SOURCE address (inverse) and on ds_read (both-sides, rule #21).

struct APtrs { const ushort* p[5]; };

template <int RELU, int SHIFT>
__global__ __launch_bounds__(256, 2) void gemm_mfma(APtrs ap, const ushort* __restrict__ WT,
                                                    const float* __restrict__ bias,
                                                    ushort* __restrict__ C, int M, int Ktot) {
  constexpr int LDA = 1 << SHIFT;
  __shared__ __align__(16) char lAb[16384];  // [128 m][64 k] bf16, swizzled
  __shared__ __align__(16) char lBb[16384];  // [128 n][64 k] bf16, swizzled
  int tid = threadIdx.x;
  int lane = tid & 63, w = tid >> 6;
  int wr = w >> 1, wc = w & 1;
  int row0 = blockIdx.x * 128, col0 = blockIdx.y * 128;

  f32x4 acc[4][4];
#pragma unroll
  for (int i = 0; i < 4; ++i)
#pragma unroll
    for (int n = 0; n < 4; ++n) acc[i][n] = {0.f, 0.f, 0.f, 0.f};

  for (int k0 = 0; k0 < Ktot; k0 += 64) {
    const char* Ab = (const char*)ap.p[k0 >> SHIFT];
    int ka = k0 & (LDA - 1);
    __syncthreads();
    // stage A: 16 KB = 4 chunks x (256 threads x 16 B); sliced source layout
#pragma unroll
    for (int c = 0; c < 4; ++c) {
      int base = c * 4096 + w * 1024;
      int off = base + lane * 16;
      int row = off >> 7, within = off & 127;
      int lw = within ^ ((row & 7) << 4);     // logical k-byte in row
      int grow = row0 + row; if (grow >= M) grow = M - 1;
      int rb = (ka << 1) + lw;                // byte offset within logical row
      const char* g = Ab + ((size_t)(rb >> 6) * M + grow) * 64 + (rb & 63);
      __builtin_amdgcn_global_load_lds((gvoid*)g, (svoid*)(lAb + base), 16, 0, 0);
    }
    // stage B: 16 KB = 4 chunks (dense WT)
#pragma unroll
    for (int c = 0; c < 4; ++c) {
      int base = c * 4096 + w * 1024;
      int off = base + lane * 16;
      int n = off >> 7, within = off & 127;
      int lw = within ^ ((n & 7) << 4);
      const ushort* g = WT + (size_t)(col0 + n) * Ktot + k0 + (lw >> 1);
      __builtin_amdgcn_global_load_lds((gvoid*)g, (svoid*)(lBb + base), 16, 0, 0);
    }
    asm volatile("s_waitcnt vmcnt(0)" ::: "memory");
    __syncthreads();
#pragma unroll
    for (int s = 0; s < 2; ++s) {
      int kb = (s << 6) + ((lane >> 4) << 4);
      bf16x8 af[4], bfr[4];
#pragma unroll
      for (int i = 0; i < 4; ++i) {
        int mrow = (wr << 6) + (i << 4) + (lane & 15);
        af[i] = *(const bf16x8*)(lAb + (mrow << 7) + (kb ^ ((mrow & 7) << 4)));
      }
#pragma unroll
      for (int n = 0; n < 4; ++n) {
        int ncol = (wc << 6) + (n << 4) + (lane & 15);
        bfr[n] = *(const bf16x8*)(lBb + (ncol << 7) + (kb ^ ((ncol & 7) << 4)));
      }
#pragma unroll
      for (int i = 0; i < 4; ++i)
#pragma unroll
        for (int n = 0; n < 4; ++n)
          acc[i][n] = __builtin_amdgcn_mfma_f32_16x16x32_bf16(af[i], bfr[n], acc[i][n], 0, 0, 0);
    }
  }
  // epilogue: bias + act + sliced bf16 store. D: col=lane&15, row=(lane>>4)*4+r
  int cb = col0 + (wc << 6) + (lane & 15);
  float bv[4];
#pragma unroll
  for (int n = 0; n < 4; ++n) bv[n] = bias[cb + (n << 4)];
#pragma unroll
  for (int i = 0; i < 4; ++i) {
    int rbase = row0 + (wr << 6) + (i << 4) + ((lane >> 4) << 2);
#pragma unroll
    for (int r = 0; r < 4; ++r) {
      int row = rbase + r;
      if (row < M) {
#pragma unroll
        for (int n = 0; n < 4; ++n) {
          float v = acc[i][n][r] + bv[n];
          if (RELU) v = fmaxf(v, 0.f);
          int c = cb + (n << 4);
          C[((size_t)(c >> 5) * M + row) * 32 + ((c >> 1) & 15) * 2 + (c & 1)] = f2b(v);
        }
      }
    }
  }
}

// ---------------- fused pool + head (sliced input) ----------------

__global__ __launch_bounds__(256) void head_kernel(const uint* __restrict__ h,
                                                   const int* __restrict__ bnd,
                                                   const float* __restrict__ lw1,
                                                   const float* __restrict__ lb1,
                                                   const float* __restrict__ lw2,
                                                   const float* __restrict__ lb2,
                                                   float* __restrict__ out, int nb) {
  int g = blockIdx.x;
  int j = threadIdx.x;  // 256 -> feature j
  __shared__ float gs[256];
  __shared__ float red[256];
  int s = bnd[g], e = bnd[g + 1];
  int ui = j >> 1, half = j & 1;
  const uint* hs = h + (size_t)(ui >> 4) * nb * 16 + (ui & 15);
  float acc = 0.f;
  int i = s;
  for (; i + 4 <= e; i += 4) {
    uint p0 = hs[(size_t)(i + 0) * 16];
    uint p1 = hs[(size_t)(i + 1) * 16];
    uint p2 = hs[(size_t)(i + 2) * 16];
    uint p3 = hs[(size_t)(i + 3) * 16];
    acc += b2f((ushort)(half ? (p0 >> 16) : (p0 & 0xFFFF)));
    acc += b2f((ushort)(half ? (p1 >> 16) : (p1 & 0xFFFF)));
    acc += b2f((ushort)(half ? (p2 >> 16) : (p2 & 0xFFFF)));
    acc += b2f((ushort)(half ? (p3 >> 16) : (p3 & 0xFFFF)));
  }
  for (; i < e; ++i) {
    uint p = hs[(size_t)i * 16];
    acc += b2f((ushort)(half ? (p >> 16) : (p & 0xFFFF)));
  }
  float c = fmaxf((float)(e - s), 1.f);
  gs[j] = fmaxf(acc / c, 0.f);
  __syncthreads();
  float t = lb1[j];
  for (int k = 0; k < 256; ++k) t = fmaf(gs[k], lw1[k * 256 + j], t);
  red[j] = t * lw2[j];
  __syncthreads();
  for (int off = 128; off > 0; off >>= 1) {
    if (j < off) red[j] += red[j + off];
    __syncthreads();
  }
  if (j == 0) out[g] = 1.f / (1.f + expf(-(red[0] + lb2[0])));
}

// ---------------- host ----------------

extern "C" void kernel_launch(void* const* d_in, const int* in_sizes, int n_in,
                              void* d_out, int out_size, void* d_ws, size_t ws_size,
                              hipStream_t stream) {
  const float* x    = (const float*)d_in[0];
  const int*   ei   = (const int*)d_in[1];
  const float* ew   = (const float*)d_in[2];
  const int*   batch= (const int*)d_in[3];
  const float* W1 = (const float*)d_in[4];
  const float* b1 = (const float*)d_in[5];
  const float* W2 = (const float*)d_in[6];
  const float* b2 = (const float*)d_in[7];
  const float* W3 = (const float*)d_in[8];
  const float* b3 = (const float*)d_in[9];
  const float* lw1 = (const float*)d_in[10];
  const float* lb1 = (const float*)d_in[11];
  const float* lw2 = (const float*)d_in[12];
  const float* lb2 = (const float*)d_in[13];
  float* out = (float*)d_out;

  const int NE  = in_sizes[2];
  const int NB  = in_sizes[3];
  const int FIN = in_sizes[0] / NB;  // 128
  const int NG  = out_size;          // 64
  const int* src = ei;
  const int* dst = ei + NE;

  char* p = (char*)d_ws;
  auto alloc = [&](size_t bytes) {
    char* q = p;
    p += (bytes + 255) & ~(size_t)255;
    return q;
  };
  char* zb = (char*)alloc((size_t)(2 * NB + 1) * 4);
  float* deg  = (float*)zb;  // becomes dis in node_kernel
  int*   cnt  = (int*)(zb + (size_t)NB * 4);
  int*   total= (int*)(zb + (size_t)2 * NB * 4);
  int*   rowstart = (int*)alloc((size_t)NB * 4);
  int*   cursor   = (int*)alloc((size_t)NB * 4);
  int2*  cv       = (int2*)alloc((size_t)NE * 8);
  int*   bnd      = (int*)alloc((size_t)(NG + 1) * 4);
  uint*  X0  = (uint*)alloc((size_t)NB * (FIN / 2) * 4);
  uint*  T1  = (uint*)alloc((size_t)NB * 128 * 4);
  uint*  T2  = (uint*)alloc((size_t)NB * 128 * 4);
  uint*  T3  = (uint*)alloc((size_t)NB * 128 * 4);
  uint*  T4  = (uint*)alloc((size_t)NB * 128 * 4);
  uint*  HA  = (uint*)alloc((size_t)NB * 128 * 4);
  uint*  HB  = (uint*)alloc((size_t)NB * 128 * 4);
  ushort* WT1 = (ushort*)alloc((size_t)256 * 5 * FIN * 2);
  ushort* WT2 = (ushort*)alloc((size_t)256 * 5 * 256 * 2);
  ushort* WT3 = (ushort*)alloc((size_t)256 * 5 * 256 * 2);

  hipMemsetAsync(zb, 0, (size_t)(2 * NB + 1) * 4, stream);

  int eb = (NE + 255) / 256;
  int nbb = (NB + 255) / 256;
  edge_kernel<<<eb, 256, 0, stream>>>(src, dst, ew, deg, cnt, NE);
  node_kernel<<<nbb, 256, 0, stream>>>(deg, cnt, rowstart, cursor, total, batch, NB, NG, bnd);
  scatter_kernel<<<eb, 256, 0, stream>>>(src, dst, ew, deg, cursor, cv, NE);

  xcvt_kernel<<<(NB * 64 + 255) / 256, 256, 0, stream>>>(x, X0, NB);
  {
    int kt1 = 5 * FIN, tot1 = 256 * kt1;
    wprep_kernel<<<(tot1 + 255) / 256, 256, 0, stream>>>(W1, WT1, 7, kt1, tot1);
    int tot2 = 256 * 1280;
    wprep2_kernel<<<(2 * tot2 + 255) / 256, 256, 0, stream>>>(W2, WT2, W3, WT3, tot2);
  }

  int rb4 = (NB + 3) / 4;
  dim3 ggrid((NB + 127) / 128, 2);

  // ---- layer 1 (Fin=128, NS=4, relu) ----
  spmm_slice<2><<<4 * rb4, 256, 0, stream>>>(rowstart, cnt, cv, X0, T1, nullptr, 1.f, NB);
  spmm_slice<2><<<4 * rb4, 256, 0, stream>>>(rowstart, cnt, cv, T1, T2, X0, 2.f, NB);
  spmm_slice<2><<<4 * rb4, 256, 0, stream>>>(rowstart, cnt, cv, T2, T3, T1, 2.f, NB);
  spmm_slice<2><<<4 * rb4, 256, 0, stream>>>(rowstart, cnt, cv, T3, T4, T2, 2.f, NB);
  {
    APtrs ap = {{(const ushort*)X0, (const ushort*)T1, (const ushort*)T2,
                 (const ushort*)T3, (const ushort*)T4}};
    gemm_mfma<1, 7><<<ggrid, 256, 0, stream>>>(ap, WT1, b1, (ushort*)HA, NB, 5 * FIN);
  }
  // ---- layer 2 (Fin=256, NS=8, no relu) ----
  spmm_slice<3><<<8 * rb4, 256, 0, stream>>>(rowstart, cnt, cv, HA, T1, nullptr, 1.f, NB);
  spmm_slice<3><<<8 * rb4, 256, 0, stream>>>(rowstart, cnt, cv, T1, T2, HA, 2.f, NB);
  spmm_slice<3><<<8 * rb4, 256, 0, stream>>>(rowstart, cnt, cv, T2, T3, T1, 2.f, NB);
  spmm_slice<3><<<8 * rb4, 256, 0, stream>>>(rowstart, cnt, cv, T3, T4, T2, 2.f, NB);
  {
    APtrs ap = {{(const ushort*)HA, (const ushort*)T1, (const ushort*)T2,
                 (const ushort*)T3, (const ushort*)T4}};
    gemm_mfma<0, 8><<<ggrid, 256, 0, stream>>>(ap, WT2, b2, (ushort*)HB, NB, 5 * 256);
  }
  // ---- layer 3 (Fin=256, NS=8, relu) ----
  spmm_slice<3><<<8 * rb4, 256, 0, stream>>>(rowstart, cnt, cv, HB, T1, nullptr, 1.f, NB);
  spmm_slice<3><<<8 * rb4, 256, 0, stream>>>(rowstart, cnt, cv, T1, T2, HB, 2.f, NB);
  spmm_slice<3><<<8 * rb4, 256, 0, stream>>>(rowstart, cnt, cv, T2, T3, T1, 2.f, NB);
  spmm_slice<3><<<8 * rb4, 256, 0, stream>>>(rowstart, cnt, cv, T3, T4, T2, 2.f, NB);
  {
    APtrs ap = {{(const ushort*)HB, (const ushort*)T1, (const ushort*)T2,
                 (const ushort*)T3, (const ushort*)T4}};
    gemm_mfma<1, 8><<<ggrid, 256, 0, stream>>>(ap, WT3, b3, (ushort*)HA, NB, 5 * 256);
  }

  head_kernel<<<NG, 256, 0, stream>>>(HA, bnd, lw1, lb1, lw2, lb2, out, NB);
}

// Round 11
// 1011.994 us; speedup vs baseline: 1.8860x; 1.8860x over previous
//
#include <hip/hip_runtime.h>
#include <math.h>

typedef unsigned int uint;
typedef unsigned short ushort;
typedef __bf16 bf16x8 __attribute__((ext_vector_type(8)));
typedef float f32x4 __attribute__((ext_vector_type(4)));
typedef __attribute__((address_space(1))) const void gvoid;
typedef __attribute__((address_space(3))) void svoid;

__device__ __forceinline__ float b2f(ushort u) {
  uint v = ((uint)u) << 16;
  return __uint_as_float(v);
}
__device__ __forceinline__ ushort f2b(float f) {
  uint u = __float_as_uint(f);
  u += 0x7FFFu + ((u >> 16) & 1u);  // RNE
  return (ushort)(u >> 16);
}
__device__ __forceinline__ uint pack2(float a, float b) {
  return (uint)f2b(a) | ((uint)f2b(b) << 16);
}

// ---------------- preprocessing ----------------
// Histograms partitioned 8-way by blockIdx&7: under round-robin block->XCD
// dispatch each partition's 200KB stays in one XCD's L2 (correctness does not
// depend on the mapping). node_kernel reduces the partitions.

__global__ void edge_kernel(const int* __restrict__ src, const int* __restrict__ dst,
                            const float* __restrict__ w, float* __restrict__ degp,
                            int* __restrict__ cntp, int ne, int nb) {
  int e = blockIdx.x * blockDim.x + threadIdx.x;
  if (e < ne) {
    int part = blockIdx.x & 7;
    atomicAdd(&degp[(size_t)part * nb + src[e]], w[e]);
    atomicAdd(&cntp[(size_t)part * nb + dst[e]], 1);
  }
}

__global__ __launch_bounds__(256) void node_kernel(const float* __restrict__ degp,
                                                   const int* __restrict__ cntp,
                                                   float* __restrict__ dis,
                                                   int* __restrict__ rowstart,
                                                   int* __restrict__ rowcnt,
                                                   int* __restrict__ cursor,
                                                   int* __restrict__ total,
                                                   const int* __restrict__ batch,
                                                   int nb, int ng, int* __restrict__ bnd) {
  __shared__ int ls[256];
  __shared__ int base;
  int tid = threadIdx.x;
  int i = blockIdx.x * 256 + tid;
  int c = 0;
  float d = 0.f;
  if (i < nb) {
#pragma unroll
    for (int p = 0; p < 8; ++p) {
      c += cntp[(size_t)p * nb + i];
      d += degp[(size_t)p * nb + i];
    }
  }
  ls[tid] = c;
  __syncthreads();
  for (int off = 1; off < 256; off <<= 1) {
    int v = (tid >= off) ? ls[tid - off] : 0;
    __syncthreads();
    ls[tid] += v;
    __syncthreads();
  }
  if (tid == 255) base = atomicAdd(total, ls[255]);
  __syncthreads();
  if (i < nb) {
    int pos = base + ls[tid] - c;
    rowstart[i] = pos;
    cursor[i] = pos;
    rowcnt[i] = c;
    dis[i] = d > 0.f ? rsqrtf(fmaxf(d, 1e-30f)) : 0.f;
  }
  if (blockIdx.x == 0 && tid <= ng) {
    int lo = 0, hi = nb;
    while (lo < hi) {
      int mid = (lo + hi) >> 1;
      if (batch[mid] < tid) lo = mid + 1; else hi = mid;
    }
    bnd[tid] = lo;
  }
}

// cv[pos] = (src, -dis[s]*w*dis[d]) interleaved for uniform-load in SpMM
__global__ void scatter_kernel(const int* __restrict__ src, const int* __restrict__ dst,
                               const float* __restrict__ w, const float* __restrict__ dis,
                               int* __restrict__ cursor, int2* __restrict__ cv, int ne) {
  int e = blockIdx.x * blockDim.x + threadIdx.x;
  if (e < ne) {
    int d = dst[e], s = src[e];
    int pos = atomicAdd(&cursor[d], 1);
    float v = -(dis[s] * w[e] * dis[d]);
    cv[pos] = make_int2(s, __float_as_int(v));
  }
}

// ---------------- conversions ----------------

// x fp32 [NB][FIN] -> bf16 pairs (uint) [NB][FIN/2]
__global__ void xcvt_kernel(const float* __restrict__ x, uint* __restrict__ o, int total) {
  int i = blockIdx.x * blockDim.x + threadIdx.x;
  if (i < total) {
    float2 v = *(const float2*)(x + (size_t)i * 2);
    o[i] = pack2(v.x, v.y);
  }
}

// W fp32 [5][Fin][256] -> WT bf16 [256][Ktot], Ktot=5*Fin, k = ord*Fin+fin
__global__ void wprep_kernel(const float* __restrict__ W, ushort* __restrict__ WT,
                             int shift, int Ktot, int total) {
  int id = blockIdx.x * blockDim.x + threadIdx.x;
  if (id >= total) return;
  int n = id / Ktot;
  int k = id - n * Ktot;
  int fin = k & ((1 << shift) - 1);
  int ord = k >> shift;
  WT[id] = f2b(W[(size_t)(ord << shift) * 256 + (size_t)fin * 256 + n]);
}

__global__ void wprep2_kernel(const float* __restrict__ W2, ushort* __restrict__ WT2,
                              const float* __restrict__ W3, ushort* __restrict__ WT3,
                              int tot) {
  int id = blockIdx.x * blockDim.x + threadIdx.x;
  if (id >= 2 * tot) return;
  const float* W = (id < tot) ? W2 : W3;
  ushort* WT = (id < tot) ? WT2 : WT3;
  int t = (id < tot) ? id : id - tot;
  int n = t / 1280;
  int k = t - n * 1280;
  int fin = k & 255;
  int ord = k >> 8;
  WT[t] = f2b(W[(size_t)(ord << 8) * 256 + (size_t)fin * 256 + n]);
}

// ---------------- SpMM: one wave per row, 4 gathers in flight ----------------
// WIDE=1: F=256 (uint2/lane), WIDE=0: F=128 (uint/lane). 4 rows per 256-thr block.
// out[row] = alpha * sum val*X[col] - sub[row]

#define RFL __builtin_amdgcn_readfirstlane

template <int WIDE>
__global__ __launch_bounds__(256) void spmm_wave(const int* __restrict__ rowstart,
                                                 const int* __restrict__ rowcnt,
                                                 const int2* __restrict__ cv,
                                                 const uint* __restrict__ X,
                                                 uint* __restrict__ out,
                                                 const uint* __restrict__ sub,
                                                 float alpha, int nb) {
  int row = blockIdx.x * 4 + (threadIdx.x >> 6);
  if (row >= nb) return;
  int lane = threadIdx.x & 63;
  int e0 = RFL(rowstart[row]);
  int cnt = RFL(rowcnt[row]);
  int e1 = e0 + cnt;
  float a0 = 0.f, a1 = 0.f, a2 = 0.f, a3 = 0.f;
  int e = e0;
  if (WIDE) {
    const uint2* Xr = (const uint2*)X;
    for (; e + 4 <= e1; e += 4) {
      int2 p0 = cv[e], p1 = cv[e + 1], p2 = cv[e + 2], p3 = cv[e + 3];
      int c0 = RFL(p0.x); float v0 = __uint_as_float(RFL((uint)p0.y));
      int c1 = RFL(p1.x); float v1 = __uint_as_float(RFL((uint)p1.y));
      int c2 = RFL(p2.x); float v2 = __uint_as_float(RFL((uint)p2.y));
      int c3 = RFL(p3.x); float v3 = __uint_as_float(RFL((uint)p3.y));
      uint2 g0 = Xr[(size_t)c0 * 64 + lane];
      uint2 g1 = Xr[(size_t)c1 * 64 + lane];
      uint2 g2 = Xr[(size_t)c2 * 64 + lane];
      uint2 g3 = Xr[(size_t)c3 * 64 + lane];
      a0 = fmaf(v0, b2f((ushort)(g0.x & 0xFFFF)), a0);
      a1 = fmaf(v0, b2f((ushort)(g0.x >> 16)), a1);
      a2 = fmaf(v0, b2f((ushort)(g0.y & 0xFFFF)), a2);
      a3 = fmaf(v0, b2f((ushort)(g0.y >> 16)), a3);
      a0 = fmaf(v1, b2f((ushort)(g1.x & 0xFFFF)), a0);
      a1 = fmaf(v1, b2f((ushort)(g1.x >> 16)), a1);
      a2 = fmaf(v1, b2f((ushort)(g1.y & 0xFFFF)), a2);
      a3 = fmaf(v1, b2f((ushort)(g1.y >> 16)), a3);
      a0 = fmaf(v2, b2f((ushort)(g2.x & 0xFFFF)), a0);
      a1 = fmaf(v2, b2f((ushort)(g2.x >> 16)), a1);
      a2 = fmaf(v2, b2f((ushort)(g2.y & 0xFFFF)), a2);
      a3 = fmaf(v2, b2f((ushort)(g2.y >> 16)), a3);
      a0 = fmaf(v3, b2f((ushort)(g3.x & 0xFFFF)), a0);
      a1 = fmaf(v3, b2f((ushort)(g3.x >> 16)), a1);
      a2 = fmaf(v3, b2f((ushort)(g3.y & 0xFFFF)), a2);
      a3 = fmaf(v3, b2f((ushort)(g3.y >> 16)), a3);
    }
    for (; e < e1; ++e) {
      int2 p0 = cv[e];
      int c0 = RFL(p0.x); float v0 = __uint_as_float(RFL((uint)p0.y));
      uint2 g0 = Xr[(size_t)c0 * 64 + lane];
      a0 = fmaf(v0, b2f((ushort)(g0.x & 0xFFFF)), a0);
      a1 = fmaf(v0, b2f((ushort)(g0.x >> 16)), a1);
      a2 = fmaf(v0, b2f((ushort)(g0.y & 0xFFFF)), a2);
      a3 = fmaf(v0, b2f((ushort)(g0.y >> 16)), a3);
    }
    float r0 = alpha * a0, r1 = alpha * a1, r2 = alpha * a2, r3 = alpha * a3;
    if (sub) {
      uint2 s = ((const uint2*)sub)[(size_t)row * 64 + lane];
      r0 -= b2f((ushort)(s.x & 0xFFFF));
      r1 -= b2f((ushort)(s.x >> 16));
      r2 -= b2f((ushort)(s.y & 0xFFFF));
      r3 -= b2f((ushort)(s.y >> 16));
    }
    ((uint2*)out)[(size_t)row * 64 + lane] = make_uint2(pack2(r0, r1), pack2(r2, r3));
  } else {
    for (; e + 4 <= e1; e += 4) {
      int2 p0 = cv[e], p1 = cv[e + 1], p2 = cv[e + 2], p3 = cv[e + 3];
      int c0 = RFL(p0.x); float v0 = __uint_as_float(RFL((uint)p0.y));
      int c1 = RFL(p1.x); float v1 = __uint_as_float(RFL((uint)p1.y));
      int c2 = RFL(p2.x); float v2 = __uint_as_float(RFL((uint)p2.y));
      int c3 = RFL(p3.x); float v3 = __uint_as_float(RFL((uint)p3.y));
      uint g0 = X[(size_t)c0 * 64 + lane];
      uint g1 = X[(size_t)c1 * 64 + lane];
      uint g2 = X[(size_t)c2 * 64 + lane];
      uint g3 = X[(size_t)c3 * 64 + lane];
      a0 = fmaf(v0, b2f((ushort)(g0 & 0xFFFF)), a0);
      a1 = fmaf(v0, b2f((ushort)(g0 >> 16)), a1);
      a0 = fmaf(v1, b2f((ushort)(g1 & 0xFFFF)), a0);
      a1 = fmaf(v1, b2f((ushort)(g1 >> 16)), a1);
      a0 = fmaf(v2, b2f((ushort)(g2 & 0xFFFF)), a0);
      a1 = fmaf(v2, b2f((ushort)(g2 >> 16)), a1);
      a0 = fmaf(v3, b2f((ushort)(g3 & 0xFFFF)), a0);
      a1 = fmaf(v3, b2f((ushort)(g3 >> 16)), a1);
    }
    for (; e < e1; ++e) {
      int2 p0 = cv[e];
      int c0 = RFL(p0.x); float v0 = __uint_as_float(RFL((uint)p0.y));
      uint g0 = X[(size_t)c0 * 64 + lane];
      a0 = fmaf(v0, b2f((ushort)(g0 & 0xFFFF)), a0);
      a1 = fmaf(v0, b2f((ushort)(g0 >> 16)), a1);
    }
    float r0 = alpha * a0, r1 = alpha * a1;
    if (sub) {
      uint s = sub[(size_t)row * 64 + lane];
      r0 -= b2f((ushort)(s & 0xFFFF));
      r1 -= b2f((ushort)(s >> 16));
    }
    out[(size_t)row * 64 + lane] = pack2(r0, r1);
  }
}

// ---------------- MFMA GEMM: C[M][256] = act(sum_ord Tx_ord @ W_ord + b) -> bf16 ----------------
// A: 5 bf16 buffers [M][Fin]; WT: bf16 [256][Ktot] (K-contiguous); tile 128x128, BK=64.
// LDS linear dest for global_load_lds; XOR swizzle ((row&7)<<4) on the global
// SOURCE address (inverse) and on ds_read (both-sides, rule #21).

struct APtrs { const ushort* p[5]; };

template <int RELU, int SHIFT>
__global__ __launch_bounds__(256, 2) void gemm_mfma(APtrs ap, const ushort* __restrict__ WT,
                                                    const float* __restrict__ bias,
                                                    ushort* __restrict__ C, int M, int Ktot) {
  constexpr int LDA = 1 << SHIFT;
  __shared__ __align__(16) char lAb[16384];  // [128 m][64 k] bf16, swizzled
  __shared__ __align__(16) char lBb[16384];  // [128 n][64 k] bf16, swizzled
  int tid = threadIdx.x;
  int lane = tid & 63, w = tid >> 6;
  int wr = w >> 1, wc = w & 1;
  int row0 = blockIdx.x * 128, col0 = blockIdx.y * 128;

  f32x4 acc[4][4];
#pragma unroll
  for (int i = 0; i < 4; ++i)
#pragma unroll
    for (int n = 0; n < 4; ++n) acc[i][n] = {0.f, 0.f, 0.f, 0.f};

  for (int k0 = 0; k0 < Ktot; k0 += 64) {
    const ushort* Ab = ap.p[k0 >> SHIFT];
    int ka = k0 & (LDA - 1);
    __syncthreads();
    // stage A: 16 KB = 4 chunks x (256 threads x 16 B)
#pragma unroll
    for (int c = 0; c < 4; ++c) {
      int base = c * 4096 + w * 1024;
      int off = base + lane * 16;
      int row = off >> 7, within = off & 127;
      int lw = within ^ ((row & 7) << 4);
      int grow = row0 + row; if (grow >= M) grow = M - 1;
      const ushort* g = Ab + (size_t)grow * LDA + ka + (lw >> 1);
      __builtin_amdgcn_global_load_lds((gvoid*)g, (svoid*)(lAb + base), 16, 0, 0);
    }
    // stage B: 16 KB = 4 chunks
#pragma unroll
    for (int c = 0; c < 4; ++c) {
      int base = c * 4096 + w * 1024;
      int off = base + lane * 16;
      int n = off >> 7, within = off & 127;
      int lw = within ^ ((n & 7) << 4);
      const ushort* g = WT + (size_t)(col0 + n) * Ktot + k0 + (lw >> 1);
      __builtin_amdgcn_global_load_lds((gvoid*)g, (svoid*)(lBb + base), 16, 0, 0);
    }
    asm volatile("s_waitcnt vmcnt(0)" ::: "memory");
    __syncthreads();
#pragma unroll
    for (int s = 0; s < 2; ++s) {
      int kb = (s << 6) + ((lane >> 4) << 4);
      bf16x8 af[4], bfr[4];
#pragma unroll
      for (int i = 0; i < 4; ++i) {
        int mrow = (wr << 6) + (i << 4) + (lane & 15);
        af[i] = *(const bf16x8*)(lAb + (mrow << 7) + (kb ^ ((mrow & 7) << 4)));
      }
#pragma unroll
      for (int n = 0; n < 4; ++n) {
        int ncol = (wc << 6) + (n << 4) + (lane & 15);
        bfr[n] = *(const bf16x8*)(lBb + (ncol << 7) + (kb ^ ((ncol & 7) << 4)));
      }
#pragma unroll
      for (int i = 0; i < 4; ++i)
#pragma unroll
        for (int n = 0; n < 4; ++n)
          acc[i][n] = __builtin_amdgcn_mfma_f32_16x16x32_bf16(af[i], bfr[n], acc[i][n], 0, 0, 0);
    }
  }
  // epilogue: bias + act + bf16 store. D: col=lane&15, row=(lane>>4)*4+r
  int cb = col0 + (wc << 6) + (lane & 15);
  float bv[4];
#pragma unroll
  for (int n = 0; n < 4; ++n) bv[n] = bias[cb + (n << 4)];
#pragma unroll
  for (int i = 0; i < 4; ++i) {
    int rbase = row0 + (wr << 6) + (i << 4) + ((lane >> 4) << 2);
#pragma unroll
    for (int r = 0; r < 4; ++r) {
      int row = rbase + r;
      if (row < M) {
#pragma unroll
        for (int n = 0; n < 4; ++n) {
          float v = acc[i][n][r] + bv[n];
          if (RELU) v = fmaxf(v, 0.f);
          C[(size_t)row * 256 + cb + (n << 4)] = f2b(v);
        }
      }
    }
  }
}

// ---------------- fused pool + head: one block per graph ----------------

__global__ __launch_bounds__(256) void head_kernel(const uint* __restrict__ h,
                                                   const int* __restrict__ bnd,
                                                   const float* __restrict__ lw1,
                                                   const float* __restrict__ lb1,
                                                   const float* __restrict__ lw2,
                                                   const float* __restrict__ lb2,
                                                   float* __restrict__ out) {
  int g = blockIdx.x;
  int j = threadIdx.x;  // 256 -> feature j
  __shared__ float gs[256];
  __shared__ float red[256];
  int s = bnd[g], e = bnd[g + 1];
  int ui = j >> 1, half = j & 1;
  float acc = 0.f;
  int i = s;
  for (; i + 4 <= e; i += 4) {
    uint p0 = h[(size_t)(i + 0) * 128 + ui];
    uint p1 = h[(size_t)(i + 1) * 128 + ui];
    uint p2 = h[(size_t)(i + 2) * 128 + ui];
    uint p3 = h[(size_t)(i + 3) * 128 + ui];
    acc += b2f((ushort)(half ? (p0 >> 16) : (p0 & 0xFFFF)));
    acc += b2f((ushort)(half ? (p1 >> 16) : (p1 & 0xFFFF)));
    acc += b2f((ushort)(half ? (p2 >> 16) : (p2 & 0xFFFF)));
    acc += b2f((ushort)(half ? (p3 >> 16) : (p3 & 0xFFFF)));
  }
  for (; i < e; ++i) {
    uint p = h[(size_t)i * 128 + ui];
    acc += b2f((ushort)(half ? (p >> 16) : (p & 0xFFFF)));
  }
  float c = fmaxf((float)(e - s), 1.f);
  gs[j] = fmaxf(acc / c, 0.f);
  __syncthreads();
  float t = lb1[j];
  for (int k = 0; k < 256; ++k) t = fmaf(gs[k], lw1[k * 256 + j], t);
  red[j] = t * lw2[j];
  __syncthreads();
  for (int off = 128; off > 0; off >>= 1) {
    if (j < off) red[j] += red[j + off];
    __syncthreads();
  }
  if (j == 0) out[g] = 1.f / (1.f + expf(-(red[0] + lb2[0])));
}

// ---------------- host ----------------

extern "C" void kernel_launch(void* const* d_in, const int* in_sizes, int n_in,
                              void* d_out, int out_size, void* d_ws, size_t ws_size,
                              hipStream_t stream) {
  const float* x    = (const float*)d_in[0];
  const int*   ei   = (const int*)d_in[1];
  const float* ew   = (const float*)d_in[2];
  const int*   batch= (const int*)d_in[3];
  const float* W1 = (const float*)d_in[4];
  const float* b1 = (const float*)d_in[5];
  const float* W2 = (const float*)d_in[6];
  const float* b2 = (const float*)d_in[7];
  const float* W3 = (const float*)d_in[8];
  const float* b3 = (const float*)d_in[9];
  const float* lw1 = (const float*)d_in[10];
  const float* lb1 = (const float*)d_in[11];
  const float* lw2 = (const float*)d_in[12];
  const float* lb2 = (const float*)d_in[13];
  float* out = (float*)d_out;

  const int NE  = in_sizes[2];
  const int NB  = in_sizes[3];
  const int FIN = in_sizes[0] / NB;  // 128
  const int NG  = out_size;          // 64
  const int* src = ei;
  const int* dst = ei + NE;

  char* p = (char*)d_ws;
  auto alloc = [&](size_t bytes) {
    char* q = p;
    p += (bytes + 255) & ~(size_t)255;
    return q;
  };
  // zero block: degp[8][NB] f32 | cntp[8][NB] i32 | total i32
  char* zb = (char*)alloc((size_t)(16 * NB + 1) * 4);
  float* degp = (float*)zb;
  int*   cntp = (int*)(zb + (size_t)8 * NB * 4);
  int*   total= (int*)(zb + (size_t)16 * NB * 4);
  float* dis      = (float*)alloc((size_t)NB * 4);
  int*   rowstart = (int*)alloc((size_t)NB * 4);
  int*   rowcnt   = (int*)alloc((size_t)NB * 4);
  int*   cursor   = (int*)alloc((size_t)NB * 4);
  int2*  cv       = (int2*)alloc((size_t)NE * 8);
  int*   bnd      = (int*)alloc((size_t)(NG + 1) * 4);
  uint*  X0  = (uint*)alloc((size_t)NB * (FIN / 2) * 4);
  uint*  T1  = (uint*)alloc((size_t)NB * 128 * 4);
  uint*  T2  = (uint*)alloc((size_t)NB * 128 * 4);
  uint*  T3  = (uint*)alloc((size_t)NB * 128 * 4);
  uint*  T4  = (uint*)alloc((size_t)NB * 128 * 4);
  uint*  HA  = (uint*)alloc((size_t)NB * 128 * 4);
  uint*  HB  = (uint*)alloc((size_t)NB * 128 * 4);
  ushort* WT1 = (ushort*)alloc((size_t)256 * 5 * FIN * 2);
  ushort* WT2 = (ushort*)alloc((size_t)256 * 5 * 256 * 2);
  ushort* WT3 = (ushort*)alloc((size_t)256 * 5 * 256 * 2);

  hipMemsetAsync(zb, 0, (size_t)(16 * NB + 1) * 4, stream);

  int eb = (NE + 255) / 256;
  int nbb = (NB + 255) / 256;
  edge_kernel<<<eb, 256, 0, stream>>>(src, dst, ew, degp, cntp, NE, NB);
  node_kernel<<<nbb, 256, 0, stream>>>(degp, cntp, dis, rowstart, rowcnt, cursor, total,
                                       batch, NB, NG, bnd);
  scatter_kernel<<<eb, 256, 0, stream>>>(src, dst, ew, dis, cursor, cv, NE);

  int xcnt = NB * (FIN / 2);
  xcvt_kernel<<<(xcnt + 255) / 256, 256, 0, stream>>>(x, X0, xcnt);
  {
    int kt1 = 5 * FIN, tot1 = 256 * kt1;
    wprep_kernel<<<(tot1 + 255) / 256, 256, 0, stream>>>(W1, WT1, 7, kt1, tot1);
    int tot2 = 256 * 1280;
    wprep2_kernel<<<(2 * tot2 + 255) / 256, 256, 0, stream>>>(W2, WT2, W3, WT3, tot2);
  }

  int sgrid = (NB + 3) / 4;
  dim3 ggrid((NB + 127) / 128, 2);

  // ---- layer 1 (Fin=128, relu) ----
  spmm_wave<0><<<sgrid, 256, 0, stream>>>(rowstart, rowcnt, cv, X0, T1, nullptr, 1.f, NB);
  spmm_wave<0><<<sgrid, 256, 0, stream>>>(rowstart, rowcnt, cv, T1, T2, X0, 2.f, NB);
  spmm_wave<0><<<sgrid, 256, 0, stream>>>(rowstart, rowcnt, cv, T2, T3, T1, 2.f, NB);
  spmm_wave<0><<<sgrid, 256, 0, stream>>>(rowstart, rowcnt, cv, T3, T4, T2, 2.f, NB);
  {
    APtrs ap = {{(const ushort*)X0, (const ushort*)T1, (const ushort*)T2,
                 (const ushort*)T3, (const ushort*)T4}};
    gemm_mfma<1, 7><<<ggrid, 256, 0, stream>>>(ap, WT1, b1, (ushort*)HA, NB, 5 * FIN);
  }
  // ---- layer 2 (Fin=256, no relu) ----
  spmm_wave<1><<<sgrid, 256, 0, stream>>>(rowstart, rowcnt, cv, HA, T1, nullptr, 1.f, NB);
  spmm_wave<1><<<sgrid, 256, 0, stream>>>(rowstart, rowcnt, cv, T1, T2, HA, 2.f, NB);
  spmm_wave<1><<<sgrid, 256, 0, stream>>>(rowstart, rowcnt, cv, T2, T3, T1, 2.f, NB);
  spmm_wave<1><<<sgrid, 256, 0, stream>>>(rowstart, rowcnt, cv, T3, T4, T2, 2.f, NB);
  {
    APtrs ap = {{(const ushort*)HA, (const ushort*)T1, (const ushort*)T2,
                 (const ushort*)T3, (const ushort*)T4}};
    gemm_mfma<0, 8><<<ggrid, 256, 0, stream>>>(ap, WT2, b2, (ushort*)HB, NB, 5 * 256);
  }
  // ---- layer 3 (Fin=256, relu) ----
  spmm_wave<1><<<sgrid, 256, 0, stream>>>(rowstart, rowcnt, cv, HB, T1, nullptr, 1.f, NB);
  spmm_wave<1><<<sgrid, 256, 0, stream>>>(rowstart, rowcnt, cv, T1, T2, HB, 2.f, NB);
  spmm_wave<1><<<sgrid, 256, 0, stream>>>(rowstart, rowcnt, cv, T2, T3, T1, 2.f, NB);
  spmm_wave<1><<<sgrid, 256, 0, stream>>>(rowstart, rowcnt, cv, T3, T4, T2, 2.f, NB);
  {
    APtrs ap = {{(const ushort*)HB, (const ushort*)T1, (const ushort*)T2,
                 (const ushort*)T3, (const ushort*)T4}};
    gemm_mfma<1, 8><<<ggrid, 256, 0, stream>>>(ap, WT3, b3, (ushort*)HA, NB, 5 * 256);
  }

  head_kernel<<<NG, 256, 0, stream>>>(HA, bnd, lw1, lb1, lw2, lb2, out);
}

// Round 13
// 991.724 us; speedup vs baseline: 1.9245x; 1.0204x over previous
//
#include <hip/hip_runtime.h>
#include <math.h>

typedef unsigned int uint;
typedef unsigned short ushort;
typedef __bf16 bf16x8 __attribute__((ext_vector_type(8)));
typedef float f32x4 __attribute__((ext_vector_type(4)));
typedef __attribute__((address_space(1))) const void gvoid;
typedef __attribute__((address_space(3))) void svoid;

__device__ __forceinline__ float b2f(ushort u) {
  uint v = ((uint)u) << 16;
  return __uint_as_float(v);
}
__device__ __forceinline__ ushort f2b(float f) {
  uint u = __float_as_uint(f);
  u += 0x7FFFu + ((u >> 16) & 1u);  // RNE
  return (ushort)(u >> 16);
}
__device__ __forceinline__ uint pack2(float a, float b) {
  return (uint)f2b(a) | ((uint)f2b(b) << 16);
}

// ---------------- preprocessing ----------------
// Histogram atomics execute memory-side (WRITE_SIZE shows 32B/op regardless of
// partitioning — round-11 counters); partitioning kept since it benched 71us.

__global__ void edge_kernel(const int* __restrict__ src, const int* __restrict__ dst,
                            const float* __restrict__ w, float* __restrict__ degp,
                            int* __restrict__ cntp, int ne, int nb) {
  int e = blockIdx.x * blockDim.x + threadIdx.x;
  if (e < ne) {
    int part = blockIdx.x & 7;
    atomicAdd(&degp[(size_t)part * nb + src[e]], w[e]);
    atomicAdd(&cntp[(size_t)part * nb + dst[e]], 1);
  }
}

__global__ __launch_bounds__(256) void node_kernel(const float* __restrict__ degp,
                                                   const int* __restrict__ cntp,
                                                   float* __restrict__ dis,
                                                   int* __restrict__ rowstart,
                                                   int* __restrict__ rowcnt,
                                                   int* __restrict__ cursor,
                                                   int* __restrict__ total,
                                                   const int* __restrict__ batch,
                                                   int nb, int ng, int* __restrict__ bnd) {
  __shared__ int ls[256];
  __shared__ int base;
  int tid = threadIdx.x;
  int i = blockIdx.x * 256 + tid;
  int c = 0;
  float d = 0.f;
  if (i < nb) {
#pragma unroll
    for (int p = 0; p < 8; ++p) {
      c += cntp[(size_t)p * nb + i];
      d += degp[(size_t)p * nb + i];
    }
  }
  ls[tid] = c;
  __syncthreads();
  for (int off = 1; off < 256; off <<= 1) {
    int v = (tid >= off) ? ls[tid - off] : 0;
    __syncthreads();
    ls[tid] += v;
    __syncthreads();
  }
  if (tid == 255) base = atomicAdd(total, ls[255]);
  __syncthreads();
  if (i < nb) {
    int pos = base + ls[tid] - c;
    rowstart[i] = pos;
    cursor[i] = pos;
    rowcnt[i] = c;
    dis[i] = d > 0.f ? rsqrtf(fmaxf(d, 1e-30f)) : 0.f;
  }
  if (blockIdx.x == 0 && tid <= ng) {
    int lo = 0, hi = nb;
    while (lo < hi) {
      int mid = (lo + hi) >> 1;
      if (batch[mid] < tid) lo = mid + 1; else hi = mid;
    }
    bnd[tid] = lo;
  }
}

// cv[pos] = (src, -dis[s]*w*dis[d]) interleaved for uniform-load in SpMM
__global__ void scatter_kernel(const int* __restrict__ src, const int* __restrict__ dst,
                               const float* __restrict__ w, const float* __restrict__ dis,
                               int* __restrict__ cursor, int2* __restrict__ cv, int ne) {
  int e = blockIdx.x * blockDim.x + threadIdx.x;
  if (e < ne) {
    int d = dst[e], s = src[e];
    int pos = atomicAdd(&cursor[d], 1);
    float v = -(dis[s] * w[e] * dis[d]);
    cv[pos] = make_int2(s, __float_as_int(v));
  }
}

// ---------------- fused conversions: xcvt + all weight preps in one launch ----
// id ranges: [0, nb*FIN/2)           -> x fp32 -> bf16 pairs
//            [.., +256*5*FIN)        -> W1 -> WT1 [256][5*FIN]
//            [.., +2*256*1280)       -> W2/W3 -> WT2/WT3 [256][1280]

__global__ void prep_kernel(const float* __restrict__ x, uint* __restrict__ X0,
                            const float* __restrict__ W1, ushort* __restrict__ WT1,
                            const float* __restrict__ W2, ushort* __restrict__ WT2,
                            const float* __restrict__ W3, ushort* __restrict__ WT3,
                            int xcnt, int tot1, int tot2) {
  int id = blockIdx.x * blockDim.x + threadIdx.x;
  if (id < xcnt) {
    float2 v = *(const float2*)(x + (size_t)id * 2);
    X0[id] = pack2(v.x, v.y);
    return;
  }
  id -= xcnt;
  if (id < tot1) {
    int kt1 = tot1 >> 8;          // 5*FIN
    int n = id / kt1;
    int k = id - n * kt1;
    int fin = k & ((kt1 / 5) - 1);
    int ord = k / (kt1 / 5);
    WT1[id] = f2b(W1[(size_t)ord * (kt1 / 5) * 256 + (size_t)fin * 256 + n]);
    return;
  }
  id -= tot1;
  if (id >= 2 * tot2) return;
  const float* W = (id < tot2) ? W2 : W3;
  ushort* WT = (id < tot2) ? WT2 : WT3;
  int t = (id < tot2) ? id : id - tot2;
  int n = t / 1280;
  int k = t - n * 1280;
  int fin = k & 255;
  int ord = k >> 8;
  WT[t] = f2b(W[(size_t)(ord << 8) * 256 + (size_t)fin * 256 + n]);
}

// ---------------- SpMM: one wave per row, 4 gathers in flight ----------------
// WIDE=1: F=256 (uint2/lane), WIDE=0: F=128 (uint/lane). 4 rows per 256-thr block.

#define RFL __builtin_amdgcn_readfirstlane

template <int WIDE>
__global__ __launch_bounds__(256) void spmm_wave(const int* __restrict__ rowstart,
                                                 const int* __restrict__ rowcnt,
                                                 const int2* __restrict__ cv,
                                                 const uint* __restrict__ X,
                                                 uint* __restrict__ out,
                                                 const uint* __restrict__ sub,
                                                 float alpha, int nb) {
  int row = blockIdx.x * 4 + (threadIdx.x >> 6);
  if (row >= nb) return;
  int lane = threadIdx.x & 63;
  int e0 = RFL(rowstart[row]);
  int cnt = RFL(rowcnt[row]);
  int e1 = e0 + cnt;
  float a0 = 0.f, a1 = 0.f, a2 = 0.f, a3 = 0.f;
  int e = e0;
  if (WIDE) {
    const uint2* Xr = (const uint2*)X;
    for (; e + 4 <= e1; e += 4) {
      int2 p0 = cv[e], p1 = cv[e + 1], p2 = cv[e + 2], p3 = cv[e + 3];
      int c0 = RFL(p0.x); float v0 = __uint_as_float(RFL((uint)p0.y));
      int c1 = RFL(p1.x); float v1 = __uint_as_float(RFL((uint)p1.y));
      int c2 = RFL(p2.x); float v2 = __uint_as_float(RFL((uint)p2.y));
      int c3 = RFL(p3.x); float v3 = __uint_as_float(RFL((uint)p3.y));
      uint2 g0 = Xr[(size_t)c0 * 64 + lane];
      uint2 g1 = Xr[(size_t)c1 * 64 + lane];
      uint2 g2 = Xr[(size_t)c2 * 64 + lane];
      uint2 g3 = Xr[(size_t)c3 * 64 + lane];
      a0 = fmaf(v0, b2f((ushort)(g0.x & 0xFFFF)), a0);
      a1 = fmaf(v0, b2f((ushort)(g0.x >> 16)), a1);
      a2 = fmaf(v0, b2f((ushort)(g0.y & 0xFFFF)), a2);
      a3 = fmaf(v0, b2f((ushort)(g0.y >> 16)), a3);
      a0 = fmaf(v1, b2f((ushort)(g1.x & 0xFFFF)), a0);
      a1 = fmaf(v1, b2f((ushort)(g1.x >> 16)), a1);
      a2 = fmaf(v1, b2f((ushort)(g1.y & 0xFFFF)), a2);
      a3 = fmaf(v1, b2f((ushort)(g1.y >> 16)), a3);
      a0 = fmaf(v2, b2f((ushort)(g2.x & 0xFFFF)), a0);
      a1 = fmaf(v2, b2f((ushort)(g2.x >> 16)), a1);
      a2 = fmaf(v2, b2f((ushort)(g2.y & 0xFFFF)), a2);
      a3 = fmaf(v2, b2f((ushort)(g2.y >> 16)), a3);
      a0 = fmaf(v3, b2f((ushort)(g3.x & 0xFFFF)), a0);
      a1 = fmaf(v3, b2f((ushort)(g3.x >> 16)), a1);
      a2 = fmaf(v3, b2f((ushort)(g3.y & 0xFFFF)), a2);
      a3 = fmaf(v3, b2f((ushort)(g3.y >> 16)), a3);
    }
    for (; e < e1; ++e) {
      int2 p0 = cv[e];
      int c0 = RFL(p0.x); float v0 = __uint_as_float(RFL((uint)p0.y));
      uint2 g0 = Xr[(size_t)c0 * 64 + lane];
      a0 = fmaf(v0, b2f((ushort)(g0.x & 0xFFFF)), a0);
      a1 = fmaf(v0, b2f((ushort)(g0.x >> 16)), a1);
      a2 = fmaf(v0, b2f((ushort)(g0.y & 0xFFFF)), a2);
      a3 = fmaf(v0, b2f((ushort)(g0.y >> 16)), a3);
    }
    float r0 = alpha * a0, r1 = alpha * a1, r2 = alpha * a2, r3 = alpha * a3;
    if (sub) {
      uint2 s = ((const uint2*)sub)[(size_t)row * 64 + lane];
      r0 -= b2f((ushort)(s.x & 0xFFFF));
      r1 -= b2f((ushort)(s.x >> 16));
      r2 -= b2f((ushort)(s.y & 0xFFFF));
      r3 -= b2f((ushort)(s.y >> 16));
    }
    ((uint2*)out)[(size_t)row * 64 + lane] = make_uint2(pack2(r0, r1), pack2(r2, r3));
  } else {
    for (; e + 4 <= e1; e += 4) {
      int2 p0 = cv[e], p1 = cv[e + 1], p2 = cv[e + 2], p3 = cv[e + 3];
      int c0 = RFL(p0.x); float v0 = __uint_as_float(RFL((uint)p0.y));
      int c1 = RFL(p1.x); float v1 = __uint_as_float(RFL((uint)p1.y));
      int c2 = RFL(p2.x); float v2 = __uint_as_float(RFL((uint)p2.y));
      int c3 = RFL(p3.x); float v3 = __uint_as_float(RFL((uint)p3.y));
      uint g0 = X[(size_t)c0 * 64 + lane];
      uint g1 = X[(size_t)c1 * 64 + lane];
      uint g2 = X[(size_t)c2 * 64 + lane];
      uint g3 = X[(size_t)c3 * 64 + lane];
      a0 = fmaf(v0, b2f((ushort)(g0 & 0xFFFF)), a0);
      a1 = fmaf(v0, b2f((ushort)(g0 >> 16)), a1);
      a0 = fmaf(v1, b2f((ushort)(g1 & 0xFFFF)), a0);
      a1 = fmaf(v1, b2f((ushort)(g1 >> 16)), a1);
      a0 = fmaf(v2, b2f((ushort)(g2 & 0xFFFF)), a0);
      a1 = fmaf(v2, b2f((ushort)(g2 >> 16)), a1);
      a0 = fmaf(v3, b2f((ushort)(g3 & 0xFFFF)), a0);
      a1 = fmaf(v3, b2f((ushort)(g3 >> 16)), a1);
    }
    for (; e < e1; ++e) {
      int2 p0 = cv[e];
      int c0 = RFL(p0.x); float v0 = __uint_as_float(RFL((uint)p0.y));
      uint g0 = X[(size_t)c0 * 64 + lane];
      a0 = fmaf(v0, b2f((ushort)(g0 & 0xFFFF)), a0);
      a1 = fmaf(v0, b2f((ushort)(g0 >> 16)), a1);
    }
    float r0 = alpha * a0, r1 = alpha * a1;
    if (sub) {
      uint s = sub[(size_t)row * 64 + lane];
      r0 -= b2f((ushort)(s & 0xFFFF));
      r1 -= b2f((ushort)(s >> 16));
    }
    out[(size_t)row * 64 + lane] = pack2(r0, r1);
  }
}

// ---------------- MFMA GEMM, 128x256 tile (full N): A staged ONCE ----------------
// A: 5 bf16 buffers [M][Fin]; WT: bf16 [256][Ktot]; BK=64; 4 waves 2x2, each 64x128.
// LDS linear dest for global_load_lds; XOR swizzle ((row&7)<<4) on global SOURCE
// (inverse) and on ds_read (both-sides, rule #21).

struct APtrs { const ushort* p[5]; };

template <int RELU, int SHIFT>
__global__ __launch_bounds__(256, 2) void gemm_mfma(APtrs ap, const ushort* __restrict__ WT,
                                                    const float* __restrict__ bias,
                                                    ushort* __restrict__ C, int M, int Ktot) {
  constexpr int LDA = 1 << SHIFT;
  __shared__ __align__(16) char lAb[16384];  // [128 m][64 k] bf16, swizzled
  __shared__ __align__(16) char lBb[32768];  // [256 n][64 k] bf16, swizzled
  int tid = threadIdx.x;
  int lane = tid & 63, w = tid >> 6;
  int wr = w >> 1, wc = w & 1;
  int row0 = blockIdx.x * 128;

  f32x4 acc[4][8];
#pragma unroll
  for (int i = 0; i < 4; ++i)
#pragma unroll
    for (int n = 0; n < 8; ++n) acc[i][n] = {0.f, 0.f, 0.f, 0.f};

  for (int k0 = 0; k0 < Ktot; k0 += 64) {
    const ushort* Ab = ap.p[k0 >> SHIFT];
    int ka = k0 & (LDA - 1);
    __syncthreads();
    // stage A: 16 KB = 4 chunks x (256 threads x 16 B)
#pragma unroll
    for (int c = 0; c < 4; ++c) {
      int base = c * 4096 + w * 1024;
      int off = base + lane * 16;
      int row = off >> 7, within = off & 127;
      int lw = within ^ ((row & 7) << 4);
      int grow = row0 + row; if (grow >= M) grow = M - 1;
      const ushort* g = Ab + (size_t)grow * LDA + ka + (lw >> 1);
      __builtin_amdgcn_global_load_lds((gvoid*)g, (svoid*)(lAb + base), 16, 0, 0);
    }
    // stage B: 32 KB = 8 chunks (all 256 cols)
#pragma unroll
    for (int c = 0; c < 8; ++c) {
      int base = c * 4096 + w * 1024;
      int off = base + lane * 16;
      int n = off >> 7, within = off & 127;
      int lw = within ^ ((n & 7) << 4);
      const ushort* g = WT + (size_t)n * Ktot + k0 + (lw >> 1);
      __builtin_amdgcn_global_load_lds((gvoid*)g, (svoid*)(lBb + base), 16, 0, 0);
    }
    asm volatile("s_waitcnt vmcnt(0)" ::: "memory");
    __syncthreads();
#pragma unroll
    for (int s = 0; s < 2; ++s) {
      int kb = (s << 6) + ((lane >> 4) << 4);
      bf16x8 af[4], bfr[8];
#pragma unroll
      for (int i = 0; i < 4; ++i) {
        int mrow = (wr << 6) + (i << 4) + (lane & 15);
        af[i] = *(const bf16x8*)(lAb + (mrow << 7) + (kb ^ ((mrow & 7) << 4)));
      }
#pragma unroll
      for (int n = 0; n < 8; ++n) {
        int ncol = (wc << 7) + (n << 4) + (lane & 15);
        bfr[n] = *(const bf16x8*)(lBb + (ncol << 7) + (kb ^ ((ncol & 7) << 4)));
      }
#pragma unroll
      for (int i = 0; i < 4; ++i)
#pragma unroll
        for (int n = 0; n < 8; ++n)
          acc[i][n] = __builtin_amdgcn_mfma_f32_16x16x32_bf16(af[i], bfr[n], acc[i][n], 0, 0, 0);
    }
  }
  // epilogue: bias + act + bf16 store. D: col=lane&15, row=(lane>>4)*4+r
  int cb0 = (wc << 7) + (lane & 15);
  float bv[8];
#pragma unroll
  for (int n = 0; n < 8; ++n) bv[n] = bias[cb0 + (n << 4)];
#pragma unroll
  for (int i = 0; i < 4; ++i) {
    int rbase = row0 + (wr << 6) + (i << 4) + ((lane >> 4) << 2);
#pragma unroll
    for (int r = 0; r < 4; ++r) {
      int row = rbase + r;
      if (row < M) {
#pragma unroll
        for (int n = 0; n < 8; ++n) {
          float v = acc[i][n][r] + bv[n];
          if (RELU) v = fmaxf(v, 0.f);
          C[(size_t)row * 256 + cb0 + (n << 4)] = f2b(v);
        }
      }
    }
  }
}

// ---------------- fused pool + head: one block per graph ----------------

__global__ __launch_bounds__(256) void head_kernel(const uint* __restrict__ h,
                                                   const int* __restrict__ bnd,
                                                   const float* __restrict__ lw1,
                                                   const float* __restrict__ lb1,
                                                   const float* __restrict__ lw2,
                                                   const float* __restrict__ lb2,
                                                   float* __restrict__ out) {
  int g = blockIdx.x;
  int j = threadIdx.x;  // 256 -> feature j
  __shared__ float gs[256];
  __shared__ float red[256];
  int s = bnd[g], e = bnd[g + 1];
  int ui = j >> 1, half = j & 1;
  float acc = 0.f;
  int i = s;
  for (; i + 4 <= e; i += 4) {
    uint p0 = h[(size_t)(i + 0) * 128 + ui];
    uint p1 = h[(size_t)(i + 1) * 128 + ui];
    uint p2 = h[(size_t)(i + 2) * 128 + ui];
    uint p3 = h[(size_t)(i + 3) * 128 + ui];
    acc += b2f((ushort)(half ? (p0 >> 16) : (p0 & 0xFFFF)));
    acc += b2f((ushort)(half ? (p1 >> 16) : (p1 & 0xFFFF)));
    acc += b2f((ushort)(half ? (p2 >> 16) : (p2 & 0xFFFF)));
    acc += b2f((ushort)(half ? (p3 >> 16) : (p3 & 0xFFFF)));
  }
  for (; i < e; ++i) {
    uint p = h[(size_t)i * 128 + ui];
    acc += b2f((ushort)(half ? (p >> 16) : (p & 0xFFFF)));
  }
  float c = fmaxf((float)(e - s), 1.f);
  gs[j] = fmaxf(acc / c, 0.f);
  __syncthreads();
  float t = lb1[j];
  for (int k = 0; k < 256; ++k) t = fmaf(gs[k], lw1[k * 256 + j], t);
  red[j] = t * lw2[j];
  __syncthreads();
  for (int off = 128; off > 0; off >>= 1) {
    if (j < off) red[j] += red[j + off];
    __syncthreads();
  }
  if (j == 0) out[g] = 1.f / (1.f + expf(-(red[0] + lb2[0])));
}

// ---------------- host ----------------

extern "C" void kernel_launch(void* const* d_in, const int* in_sizes, int n_in,
                              void* d_out, int out_size, void* d_ws, size_t ws_size,
                              hipStream_t stream) {
  const float* x    = (const float*)d_in[0];
  const int*   ei   = (const int*)d_in[1];
  const float* ew   = (const float*)d_in[2];
  const int*   batch= (const int*)d_in[3];
  const float* W1 = (const float*)d_in[4];
  const float* b1 = (const float*)d_in[5];
  const float* W2 = (const float*)d_in[6];
  const float* b2 = (const float*)d_in[7];
  const float* W3 = (const float*)d_in[8];
  const float* b3 = (const float*)d_in[9];
  const float* lw1 = (const float*)d_in[10];
  const float* lb1 = (const float*)d_in[11];
  const float* lw2 = (const float*)d_in[12];
  const float* lb2 = (const float*)d_in[13];
  float* out = (float*)d_out;

  const int NE  = in_sizes[2];
  const int NB  = in_sizes[3];
  const int FIN = in_sizes[0] / NB;  // 128
  const int NG  = out_size;          // 64
  const int* src = ei;
  const int* dst = ei + NE;

  char* p = (char*)d_ws;
  auto alloc = [&](size_t bytes) {
    char* q = p;
    p += (bytes + 255) & ~(size_t)255;
    return q;
  };
  // zero block: degp[8][NB] f32 | cntp[8][NB] i32 | total i32
  char* zb = (char*)alloc((size_t)(16 * NB + 1) * 4);
  float* degp = (float*)zb;
  int*   cntp = (int*)(zb + (size_t)8 * NB * 4);
  int*   total= (int*)(zb + (size_t)16 * NB * 4);
  float* dis      = (float*)alloc((size_t)NB * 4);
  int*   rowstart = (int*)alloc((size_t)NB * 4);
  int*   rowcnt   = (int*)alloc((size_t)NB * 4);
  int*   cursor   = (int*)alloc((size_t)NB * 4);
  int2*  cv       = (int2*)alloc((size_t)NE * 8);
  int*   bnd      = (int*)alloc((size_t)(NG + 1) * 4);
  uint*  X0  = (uint*)alloc((size_t)NB * (FIN / 2) * 4);
  uint*  T1  = (uint*)alloc((size_t)NB * 128 * 4);
  uint*  T2  = (uint*)alloc((size_t)NB * 128 * 4);
  uint*  T3  = (uint*)alloc((size_t)NB * 128 * 4);
  uint*  T4  = (uint*)alloc((size_t)NB * 128 * 4);
  uint*  HA  = (uint*)alloc((size_t)NB * 128 * 4);
  uint*  HB  = (uint*)alloc((size_t)NB * 128 * 4);
  ushort* WT1 = (ushort*)alloc((size_t)256 * 5 * FIN * 2);
  ushort* WT2 = (ushort*)alloc((size_t)256 * 5 * 256 * 2);
  ushort* WT3 = (ushort*)alloc((size_t)256 * 5 * 256 * 2);

  hipMemsetAsync(zb, 0, (size_t)(16 * NB + 1) * 4, stream);

  int eb = (NE + 255) / 256;
  int nbb = (NB + 255) / 256;
  edge_kernel<<<eb, 256, 0, stream>>>(src, dst, ew, degp, cntp, NE, NB);
  node_kernel<<<nbb, 256, 0, stream>>>(degp, cntp, dis, rowstart, rowcnt, cursor, total,
                                       batch, NB, NG, bnd);
  scatter_kernel<<<eb, 256, 0, stream>>>(src, dst, ew, dis, cursor, cv, NE);

  {
    int xcnt = NB * (FIN / 2);
    int tot1 = 256 * 5 * FIN;
    int tot2 = 256 * 1280;
    int ptot = xcnt + tot1 + 2 * tot2;
    prep_kernel<<<(ptot + 255) / 256, 256, 0, stream>>>(x, X0, W1, WT1, W2, WT2, W3, WT3,
                                                        xcnt, tot1, tot2);
  }

  int sgrid = (NB + 3) / 4;
  int ggrid = (NB + 127) / 128;

  // ---- layer 1 (Fin=128, relu) ----
  spmm_wave<0><<<sgrid, 256, 0, stream>>>(rowstart, rowcnt, cv, X0, T1, nullptr, 1.f, NB);
  spmm_wave<0><<<sgrid, 256, 0, stream>>>(rowstart, rowcnt, cv, T1, T2, X0, 2.f, NB);
  spmm_wave<0><<<sgrid, 256, 0, stream>>>(rowstart, rowcnt, cv, T2, T3, T1, 2.f, NB);
  spmm_wave<0><<<sgrid, 256, 0, stream>>>(rowstart, rowcnt, cv, T3, T4, T2, 2.f, NB);
  {
    APtrs ap = {{(const ushort*)X0, (const ushort*)T1, (const ushort*)T2,
                 (const ushort*)T3, (const ushort*)T4}};
    gemm_mfma<1, 7><<<ggrid, 256, 0, stream>>>(ap, WT1, b1, (ushort*)HA, NB, 5 * FIN);
  }
  // ---- layer 2 (Fin=256, no relu) ----
  spmm_wave<1><<<sgrid, 256, 0, stream>>>(rowstart, rowcnt, cv, HA, T1, nullptr, 1.f, NB);
  spmm_wave<1><<<sgrid, 256, 0, stream>>>(rowstart, rowcnt, cv, T1, T2, HA, 2.f, NB);
  spmm_wave<1><<<sgrid, 256, 0, stream>>>(rowstart, rowcnt, cv, T2, T3, T1, 2.f, NB);
  spmm_wave<1><<<sgrid, 256, 0, stream>>>(rowstart, rowcnt, cv, T3, T4, T2, 2.f, NB);
  {
    APtrs ap = {{(const ushort*)HA, (const ushort*)T1, (const ushort*)T2,
                 (const ushort*)T3, (const ushort*)T4}};
    gemm_mfma<0, 8><<<ggrid, 256, 0, stream>>>(ap, WT2, b2, (ushort*)HB, NB, 5 * 256);
  }
  // ---- layer 3 (Fin=256, relu) ----
  spmm_wave<1><<<sgrid, 256, 0, stream>>>(rowstart, rowcnt, cv, HB, T1, nullptr, 1.f, NB);
  spmm_wave<1><<<sgrid, 256, 0, stream>>>(rowstart, rowcnt, cv, T1, T2, HB, 2.f, NB);
  spmm_wave<1><<<sgrid, 256, 0, stream>>>(rowstart, rowcnt, cv, T2, T3, T1, 2.f, NB);
  spmm_wave<1><<<sgrid, 256, 0, stream>>>(rowstart, rowcnt, cv, T3, T4, T2, 2.f, NB);
  {
    APtrs ap = {{(const ushort*)HB, (const ushort*)T1, (const ushort*)T2,
                 (const ushort*)T3, (const ushort*)T4}};
    gemm_mfma<1, 8><<<ggrid, 256, 0, stream>>>(ap, WT3, b3, (ushort*)HA, NB, 5 * 256);
  }

  head_kernel<<<NG, 256, 0, stream>>>(HA, bnd, lw1, lb1, lw2, lb2, out);
}